// Round 5
// baseline (342.802 us; speedup 1.0000x reference)
//
#include <hip/hip_runtime.h>

namespace {

constexpr int kBatch  = 8192;
constexpr int kHidden = 4096;
constexpr int kSeeds  = 32;
constexpr int kChunk  = 128;
constexpr int kTpb    = 1024;   // one float4 column slot per thread (4096/4 = 1024)
constexpr int kBlocks = 512;    // 16 contiguous rows per block
constexpr int kRowsPerBlk = kBatch / kBlocks;
constexpr int kPf     = 4;      // rows batched per inner iteration

typedef float fvec4 __attribute__((ext_vector_type(4)));

// Thread t owns column quad t: elements 4t..4t+3 -> seed s = t>>5 (fixed),
// chunk offset c = 4*(t&31). Blend is out = m*x + a with per-thread constant
// (m,a) registers. Each block streams 16 contiguous rows. Plain stores (NOT
// non-temporal): lets stores complete in the XCD L2 and drain lazily; NT was
// A/B'd in rounds 2-4 and moved neither FETCH_SIZE nor dur.
// Final per-seed reduction is fused via the last-block-done pattern.
__global__ __launch_bounds__(kTpb) void kasmina_main(
    const float* __restrict__ x,
    const int*   __restrict__ life,
    const int*   __restrict__ bid,
    const int*   __restrict__ strat,
    const float* __restrict__ alpha,
    const float* __restrict__ bw,
    float*       __restrict__ out,
    float*       __restrict__ psum,    // [kSeeds][kBlocks] transposed layout
    float*       __restrict__ psumsq,  // [kSeeds][kBlocks]
    unsigned int* __restrict__ counter,
    float*       __restrict__ tail)    // [tsum(32) | tsumsq(32) | tcount(32)]
{
    const int t  = threadIdx.x;
    const int s  = t >> 5;
    const int c0 = (t & 31) * 4;

    const int   lf  = life[s];
    const bool  act = (lf >= 3) && (lf <= 6);
    const int   st  = strat[s];
    const float al  = alpha[s];
    const fvec4 w   = *reinterpret_cast<const fvec4*>(
        &bw[bid[s] * kHidden + s * kChunk + c0]);

    fvec4 mm = {1.f, 1.f, 1.f, 1.f};
    fvec4 aa = {0.f, 0.f, 0.f, 0.f};
    if (act) {
        if (st == 0) {
            mm = al * w + (1.f - al);
        } else if (st == 1) {
            mm = w;
        } else {
            aa = w;
        }
    }

    float ssum = 0.f;
    float ssq  = 0.f;

    const int r0 = blockIdx.x * kRowsPerBlk;
    const float* __restrict__ xbase = x   + (size_t)r0 * kHidden + 4 * t;
    float*       __restrict__ obase = out + (size_t)r0 * kHidden + 4 * t;

    #pragma unroll
    for (int rc = 0; rc < kRowsPerBlk; rc += kPf) {
        fvec4 xv[kPf];
        #pragma unroll
        for (int k = 0; k < kPf; ++k)
            xv[k] = *reinterpret_cast<const fvec4*>(
                xbase + (size_t)(rc + k) * kHidden);
        #pragma unroll
        for (int k = 0; k < kPf; ++k) {
            fvec4 ov;
            ov.x = fmaf(mm.x, xv[k].x, aa.x);
            ov.y = fmaf(mm.y, xv[k].y, aa.y);
            ov.z = fmaf(mm.z, xv[k].z, aa.z);
            ov.w = fmaf(mm.w, xv[k].w, aa.w);
            *reinterpret_cast<fvec4*>(obase + (size_t)(rc + k) * kHidden) = ov;
            ssum += (xv[k].x + xv[k].y) + (xv[k].z + xv[k].w);
            ssq   = fmaf(xv[k].x, xv[k].x, ssq);
            ssq   = fmaf(xv[k].y, xv[k].y, ssq);
            ssq   = fmaf(xv[k].z, xv[k].z, ssq);
            ssq   = fmaf(xv[k].w, xv[k].w, ssq);
        }
    }

    // 32-lane group reduce: lanes t..t+31 (same t>>5) share one seed; xor
    // offsets 1..16 stay within each 32-lane half of the wave64.
    #pragma unroll
    for (int off = 1; off < 32; off <<= 1) {
        ssum += __shfl_xor(ssum, off, 64);
        ssq  += __shfl_xor(ssq,  off, 64);
    }
    if ((t & 31) == 0) {
        psum[s * kBlocks + blockIdx.x]   = ssum;
        psumsq[s * kBlocks + blockIdx.x] = ssq;
    }

    // ---- fused final reduce: last block to arrive does it ----
    __shared__ int amLast;
    __threadfence();  // release partials (device scope, cross-XCD)
    if (t == 0) {
        unsigned int old = atomicAdd(counter, 1u);
        amLast = (old == (unsigned int)(gridDim.x - 1));
    }
    __syncthreads();
    if (amLast) {
        __threadfence();  // acquire all blocks' partials
        // 32 lanes per seed, each lane sums kBlocks/32 = 16 partials.
        float a = 0.f, b = 0.f;
        for (int i = (t & 31); i < kBlocks; i += 32) {
            a += psum[s * kBlocks + i];
            b += psumsq[s * kBlocks + i];
        }
        #pragma unroll
        for (int off = 1; off < 32; off <<= 1) {
            a += __shfl_xor(a, off, 64);
            b += __shfl_xor(b, off, 64);
        }
        if ((t & 31) == 0) {
            tail[s]              = a;
            tail[kSeeds + s]     = b;
            tail[2 * kSeeds + s] = (float)(kBatch * kChunk);  // 1048576.0f
        }
        if (t == 0) *counter = 0;  // reset for next replay (belt & braces)
    }
}

}  // namespace

extern "C" void kernel_launch(void* const* d_in, const int* in_sizes, int n_in,
                              void* d_out, int out_size, void* d_ws, size_t ws_size,
                              hipStream_t stream) {
    const float* x     = (const float*)d_in[0];
    const int*   life  = (const int*)d_in[1];
    const int*   bid   = (const int*)d_in[2];
    const int*   strat = (const int*)d_in[3];
    const float* alpha = (const float*)d_in[4];
    const float* bw    = (const float*)d_in[5];
    float*       out   = (float*)d_out;

    float* psum   = (float*)d_ws;                      // [32][512]
    float* psumsq = psum + (size_t)kSeeds * kBlocks;
    unsigned int* counter =
        (unsigned int*)(psumsq + (size_t)kSeeds * kBlocks);

    // Counter must start at 0 every call (d_ws is poisoned 0xAA once and
    // never re-poisoned); memset node is graph-capture legal.
    hipMemsetAsync(counter, 0, sizeof(unsigned int), stream);

    float* tail = out + (size_t)kBatch * kHidden;
    kasmina_main<<<kBlocks, kTpb, 0, stream>>>(x, life, bid, strat, alpha, bw,
                                               out, psum, psumsq, counter, tail);
}

// Round 6
// 55.463 us; speedup vs baseline: 6.1807x; 6.1807x over previous
//
#include <hip/hip_runtime.h>

namespace {

constexpr int kBatch  = 8192;
constexpr int kHidden = 4096;
constexpr int kSeeds  = 32;
constexpr int kChunk  = 128;
constexpr int kTpb    = 1024;   // one float4 column slot per thread (4096/4 = 1024)
constexpr int kBlocks = 1024;   // 8 contiguous rows per block
constexpr int kRowsPerBlk = kBatch / kBlocks;
constexpr int kPf     = 4;      // rows batched per inner iteration

typedef float fvec4 __attribute__((ext_vector_type(4)));

// Thread t owns column quad t: elements 4t..4t+3 -> seed s = t>>5 (fixed),
// chunk offset c = 4*(t&31). Blend is out = m*x + a with per-thread constant
// (m,a) registers. Each block streams 8 contiguous rows.
// NT stores: A/B'd plain-vs-NT only confounded so far; NT is the proven-49.5
// configuration (round 3). Fused last-block reduce was tried (round 5) and
// regressed 7x -- device-scope threadfence forces per-block L2 drain. Keep
// the separate tiny reduce kernel.
__global__ __launch_bounds__(kTpb) void kasmina_main(
    const float* __restrict__ x,
    const int*   __restrict__ life,
    const int*   __restrict__ bid,
    const int*   __restrict__ strat,
    const float* __restrict__ alpha,
    const float* __restrict__ bw,
    float*       __restrict__ out,
    float*       __restrict__ psum,    // [kSeeds][kBlocks] transposed layout
    float*       __restrict__ psumsq)  // [kSeeds][kBlocks]
{
    const int t  = threadIdx.x;
    const int s  = t >> 5;
    const int c0 = (t & 31) * 4;

    const int   lf  = life[s];
    const bool  act = (lf >= 3) && (lf <= 6);
    const int   st  = strat[s];
    const float al  = alpha[s];
    const fvec4 w   = *reinterpret_cast<const fvec4*>(
        &bw[bid[s] * kHidden + s * kChunk + c0]);

    fvec4 mm = {1.f, 1.f, 1.f, 1.f};
    fvec4 aa = {0.f, 0.f, 0.f, 0.f};
    if (act) {
        if (st == 0) {
            mm = al * w + (1.f - al);
        } else if (st == 1) {
            mm = w;
        } else {
            aa = w;
        }
    }

    float ssum = 0.f;
    float ssq  = 0.f;

    const int r0 = blockIdx.x * kRowsPerBlk;
    const float* __restrict__ xbase = x   + (size_t)r0 * kHidden + 4 * t;
    float*       __restrict__ obase = out + (size_t)r0 * kHidden + 4 * t;

    #pragma unroll
    for (int rc = 0; rc < kRowsPerBlk; rc += kPf) {
        fvec4 xv[kPf];
        #pragma unroll
        for (int k = 0; k < kPf; ++k)
            xv[k] = *reinterpret_cast<const fvec4*>(
                xbase + (size_t)(rc + k) * kHidden);
        #pragma unroll
        for (int k = 0; k < kPf; ++k) {
            fvec4 ov;
            ov.x = fmaf(mm.x, xv[k].x, aa.x);
            ov.y = fmaf(mm.y, xv[k].y, aa.y);
            ov.z = fmaf(mm.z, xv[k].z, aa.z);
            ov.w = fmaf(mm.w, xv[k].w, aa.w);
            __builtin_nontemporal_store(
                ov, reinterpret_cast<fvec4*>(obase + (size_t)(rc + k) * kHidden));
            ssum += (xv[k].x + xv[k].y) + (xv[k].z + xv[k].w);
            ssq   = fmaf(xv[k].x, xv[k].x, ssq);
            ssq   = fmaf(xv[k].y, xv[k].y, ssq);
            ssq   = fmaf(xv[k].z, xv[k].z, ssq);
            ssq   = fmaf(xv[k].w, xv[k].w, ssq);
        }
    }

    // 32-lane group reduce: lanes t..t+31 (same t>>5) share one seed; xor
    // offsets 1..16 stay within each 32-lane half of the wave64.
    #pragma unroll
    for (int off = 1; off < 32; off <<= 1) {
        ssum += __shfl_xor(ssum, off, 64);
        ssq  += __shfl_xor(ssq,  off, 64);
    }
    if ((t & 31) == 0) {
        psum[s * kBlocks + blockIdx.x]   = ssum;
        psumsq[s * kBlocks + blockIdx.x] = ssq;
    }
}

// One wave per seed; coalesced reads over the transposed partial layout.
__global__ __launch_bounds__(64) void kasmina_reduce(
    const float* __restrict__ psum,
    const float* __restrict__ psumsq,
    float*       __restrict__ tail,   // d_out + B*H: [tsum(32) | tsumsq(32) | tcount(32)]
    int nblk)
{
    const int s = blockIdx.x;
    const int t = threadIdx.x;
    float a = 0.f, b = 0.f;
    for (int i = t; i < nblk; i += 64) {
        a += psum[(size_t)s * nblk + i];
        b += psumsq[(size_t)s * nblk + i];
    }
    #pragma unroll
    for (int off = 1; off < 64; off <<= 1) {
        a += __shfl_xor(a, off, 64);
        b += __shfl_xor(b, off, 64);
    }
    if (t == 0) {
        tail[s]              = a;
        tail[kSeeds + s]     = b;
        tail[2 * kSeeds + s] = (float)(kBatch * kChunk);  // 1048576.0f
    }
}

}  // namespace

extern "C" void kernel_launch(void* const* d_in, const int* in_sizes, int n_in,
                              void* d_out, int out_size, void* d_ws, size_t ws_size,
                              hipStream_t stream) {
    const float* x     = (const float*)d_in[0];
    const int*   life  = (const int*)d_in[1];
    const int*   bid   = (const int*)d_in[2];
    const int*   strat = (const int*)d_in[3];
    const float* alpha = (const float*)d_in[4];
    const float* bw    = (const float*)d_in[5];
    float*       out   = (float*)d_out;

    float* psum   = (float*)d_ws;                      // [32][1024]
    float* psumsq = psum + (size_t)kSeeds * kBlocks;   // needs 256 KB total

    kasmina_main<<<kBlocks, kTpb, 0, stream>>>(x, life, bid, strat, alpha, bw,
                                               out, psum, psumsq);

    float* tail = out + (size_t)kBatch * kHidden;
    kasmina_reduce<<<kSeeds, 64, 0, stream>>>(psum, psumsq, tail, kBlocks);
}

// Round 7
// 49.811 us; speedup vs baseline: 6.8821x; 1.1135x over previous
//
#include <hip/hip_runtime.h>

namespace {

constexpr int kBatch  = 8192;
constexpr int kHidden = 4096;
constexpr int kSeeds  = 32;
constexpr int kChunk  = 128;
constexpr int kTpb    = 1024;   // one float4 column slot per thread (4096/4 = 1024)
constexpr int kBlocks = 512;    // 16 contiguous rows per block (empirical optimum:
                                //  512x16 = 49.5us; 1024x8 = 55.5us; 2048x4/256tpb = 53us)
constexpr int kRowsPerBlk = kBatch / kBlocks;
constexpr int kPf     = 4;      // rows batched per inner iteration

typedef float fvec4 __attribute__((ext_vector_type(4)));

// Thread t owns column quad t: elements 4t..4t+3 -> seed s = t>>5 (fixed),
// chunk offset c = 4*(t&31). Blend is out = m*x + a with per-thread constant
// (m,a) registers. Each block streams 16 contiguous rows.
// Notes from the session ladder:
//  - NT vs plain stores: neutral on FETCH_SIZE and dur (L3/MALL is memory-side).
//  - kPf=8 batching: neutral; compiler re-serializes (VGPR stays 32).
//  - Fused last-block reduce + __threadfence: 7x regression (per-block L2 drain).
//  - This exact config measured 49.5us = ~90% of the 266MB@6.29TB/s copy floor.
__global__ __launch_bounds__(kTpb) void kasmina_main(
    const float* __restrict__ x,
    const int*   __restrict__ life,
    const int*   __restrict__ bid,
    const int*   __restrict__ strat,
    const float* __restrict__ alpha,
    const float* __restrict__ bw,
    float*       __restrict__ out,
    float*       __restrict__ psum,    // [kSeeds][kBlocks] transposed layout
    float*       __restrict__ psumsq)  // [kSeeds][kBlocks]
{
    const int t  = threadIdx.x;
    const int s  = t >> 5;
    const int c0 = (t & 31) * 4;

    const int   lf  = life[s];
    const bool  act = (lf >= 3) && (lf <= 6);
    const int   st  = strat[s];
    const float al  = alpha[s];
    const fvec4 w   = *reinterpret_cast<const fvec4*>(
        &bw[bid[s] * kHidden + s * kChunk + c0]);

    fvec4 mm = {1.f, 1.f, 1.f, 1.f};
    fvec4 aa = {0.f, 0.f, 0.f, 0.f};
    if (act) {
        if (st == 0) {
            mm = al * w + (1.f - al);
        } else if (st == 1) {
            mm = w;
        } else {
            aa = w;
        }
    }

    float ssum = 0.f;
    float ssq  = 0.f;

    const int r0 = blockIdx.x * kRowsPerBlk;
    const float* __restrict__ xbase = x   + (size_t)r0 * kHidden + 4 * t;
    float*       __restrict__ obase = out + (size_t)r0 * kHidden + 4 * t;

    #pragma unroll
    for (int rc = 0; rc < kRowsPerBlk; rc += kPf) {
        fvec4 xv[kPf];
        #pragma unroll
        for (int k = 0; k < kPf; ++k)
            xv[k] = *reinterpret_cast<const fvec4*>(
                xbase + (size_t)(rc + k) * kHidden);
        #pragma unroll
        for (int k = 0; k < kPf; ++k) {
            fvec4 ov;
            ov.x = fmaf(mm.x, xv[k].x, aa.x);
            ov.y = fmaf(mm.y, xv[k].y, aa.y);
            ov.z = fmaf(mm.z, xv[k].z, aa.z);
            ov.w = fmaf(mm.w, xv[k].w, aa.w);
            __builtin_nontemporal_store(
                ov, reinterpret_cast<fvec4*>(obase + (size_t)(rc + k) * kHidden));
            ssum += (xv[k].x + xv[k].y) + (xv[k].z + xv[k].w);
            ssq   = fmaf(xv[k].x, xv[k].x, ssq);
            ssq   = fmaf(xv[k].y, xv[k].y, ssq);
            ssq   = fmaf(xv[k].z, xv[k].z, ssq);
            ssq   = fmaf(xv[k].w, xv[k].w, ssq);
        }
    }

    // 32-lane group reduce: lanes t..t+31 (same t>>5) share one seed; xor
    // offsets 1..16 stay within each 32-lane half of the wave64.
    #pragma unroll
    for (int off = 1; off < 32; off <<= 1) {
        ssum += __shfl_xor(ssum, off, 64);
        ssq  += __shfl_xor(ssq,  off, 64);
    }
    if ((t & 31) == 0) {
        psum[s * kBlocks + blockIdx.x]   = ssum;
        psumsq[s * kBlocks + blockIdx.x] = ssq;
    }
}

// One wave per seed; coalesced reads over the transposed partial layout.
__global__ __launch_bounds__(64) void kasmina_reduce(
    const float* __restrict__ psum,
    const float* __restrict__ psumsq,
    float*       __restrict__ tail,   // d_out + B*H: [tsum(32) | tsumsq(32) | tcount(32)]
    int nblk)
{
    const int s = blockIdx.x;
    const int t = threadIdx.x;
    float a = 0.f, b = 0.f;
    for (int i = t; i < nblk; i += 64) {
        a += psum[(size_t)s * nblk + i];
        b += psumsq[(size_t)s * nblk + i];
    }
    #pragma unroll
    for (int off = 1; off < 64; off <<= 1) {
        a += __shfl_xor(a, off, 64);
        b += __shfl_xor(b, off, 64);
    }
    if (t == 0) {
        tail[s]              = a;
        tail[kSeeds + s]     = b;
        tail[2 * kSeeds + s] = (float)(kBatch * kChunk);  // 1048576.0f
    }
}

}  // namespace

extern "C" void kernel_launch(void* const* d_in, const int* in_sizes, int n_in,
                              void* d_out, int out_size, void* d_ws, size_t ws_size,
                              hipStream_t stream) {
    const float* x     = (const float*)d_in[0];
    const int*   life  = (const int*)d_in[1];
    const int*   bid   = (const int*)d_in[2];
    const int*   strat = (const int*)d_in[3];
    const float* alpha = (const float*)d_in[4];
    const float* bw    = (const float*)d_in[5];
    float*       out   = (float*)d_out;

    float* psum   = (float*)d_ws;                      // [32][512]
    float* psumsq = psum + (size_t)kSeeds * kBlocks;   // needs 128 KB total

    kasmina_main<<<kBlocks, kTpb, 0, stream>>>(x, life, bid, strat, alpha, bw,
                                               out, psum, psumsq);

    float* tail = out + (size_t)kBatch * kHidden;
    kasmina_reduce<<<kSeeds, 64, 0, stream>>>(psum, psumsq, tail, kBlocks);
}